// Round 8
// baseline (362.789 us; speedup 1.0000x reference)
//
#include <hip/hip_runtime.h>

// Shapes (fixed per setup_inputs): n=1, C=256, t=8, h=64, w=64, heads=8, S=134
#define SS   134
#define HWP  4096     // h*w
#define THW  32768    // t*h*w

typedef float f32x4 __attribute__((ext_vector_type(4)));
typedef short bf16x8 __attribute__((ext_vector_type(8)));
typedef short bf16x4 __attribute__((ext_vector_type(4)));

__device__ __forceinline__ unsigned short f2bf(float f) {
  unsigned int u = __float_as_uint(f);
  u += 0x7fff + ((u >> 16) & 1);  // RNE (inputs are finite normals)
  return (unsigned short)(u >> 16);
}

// ---------------------------------------------------------------------------
// W -> bf16, once. Wbf lives in d_out (128 KB): attn_th2 fully overwrites O
// afterwards; stream order (w2bf -> conv -> attn_th2) makes aliasing safe.
// ---------------------------------------------------------------------------
__global__ __launch_bounds__(256) void w2bf(const float* __restrict__ W,
                                            unsigned short* __restrict__ Wbf) {
  const int i = (blockIdx.x * 256 + threadIdx.x) * 4;  // grid 64 -> 65536
  const float4 w4 = *(const float4*)&W[i];
  bf16x4 b;
  b.x = (short)f2bf(w4.x);
  b.y = (short)f2bf(w4.y);
  b.z = (short)f2bf(w4.z);
  b.w = (short)f2bf(w4.w);
  *(bf16x4*)&Wbf[i] = b;
}

// ---------------------------------------------------------------------------
// 1x1 conv v4 (unchanged): W staged once into 130KB LDS, V dbuf.
// ---------------------------------------------------------------------------
__global__ __launch_bounds__(512) void conv1x1_v4(
    const float* __restrict__ V, const unsigned short* __restrict__ Wbf,
    const float* __restrict__ bias, float* __restrict__ PV) {
  __shared__ unsigned short sW[256 * 260];   // 130 KB, row stride 260
  __shared__ unsigned short sV[2][128 * 40]; // [buf][x][c], 2 x 10 KB
  const int tid = threadIdx.x;
  const int x0 = blockIdx.x * 128;  // grid 256
  const int lane = tid & 63;
  const int wv = tid >> 6;   // 0..7
  const int m = lane & 15;   // MFMA free-dim index
  const int q = lane >> 4;   // MFMA quad 0..3

  {
    const int o = tid >> 1;
    const int half = (tid & 1) * 128;
#pragma unroll
    for (int r = 0; r < 16; ++r)
      *(bf16x8*)&sW[o * 260 + half + r * 8] =
          *(const bf16x8*)&Wbf[o * 256 + half + r * 8];
  }

  const int c_s = tid >> 4;
  const int x8 = (tid & 15) * 8;
  const float* __restrict__ vstage = V + (size_t)c_s * THW + x0 + x8;

  {
    const float4 va = *(const float4*)&vstage[0];
    const float4 vb = *(const float4*)&vstage[4];
    sV[0][(x8 + 0) * 40 + c_s] = f2bf(va.x);
    sV[0][(x8 + 1) * 40 + c_s] = f2bf(va.y);
    sV[0][(x8 + 2) * 40 + c_s] = f2bf(va.z);
    sV[0][(x8 + 3) * 40 + c_s] = f2bf(va.w);
    sV[0][(x8 + 4) * 40 + c_s] = f2bf(vb.x);
    sV[0][(x8 + 5) * 40 + c_s] = f2bf(vb.y);
    sV[0][(x8 + 6) * 40 + c_s] = f2bf(vb.z);
    sV[0][(x8 + 7) * 40 + c_s] = f2bf(vb.w);
  }
  __syncthreads();

  f32x4 acc[2][8];
#pragma unroll
  for (int i = 0; i < 2; ++i)
#pragma unroll
    for (int j = 0; j < 8; ++j)
      acc[i][j] = (f32x4){0.f, 0.f, 0.f, 0.f};

  for (int kk = 0; kk < 8; ++kk) {
    const int cur = kk & 1;
    float4 pva, pvb;
    if (kk < 7) {
      pva = *(const float4*)&vstage[(size_t)(kk + 1) * 32 * THW];
      pvb = *(const float4*)&vstage[(size_t)(kk + 1) * 32 * THW + 4];
    }
    bf16x8 fa[2], fb[8];
#pragma unroll
    for (int i = 0; i < 2; ++i)
      fa[i] = *(const bf16x8*)&sW[(wv * 32 + i * 16 + m) * 260 + kk * 32 + q * 8];
#pragma unroll
    for (int j = 0; j < 8; ++j)
      fb[j] = *(const bf16x8*)&sV[cur][(j * 16 + m) * 40 + q * 8];
#pragma unroll
    for (int i = 0; i < 2; ++i)
#pragma unroll
      for (int j = 0; j < 8; ++j)
        acc[i][j] = __builtin_amdgcn_mfma_f32_16x16x32_bf16(fa[i], fb[j], acc[i][j], 0, 0, 0);
    if (kk < 7) {
      const int nb = cur ^ 1;
      sV[nb][(x8 + 0) * 40 + c_s] = f2bf(pva.x);
      sV[nb][(x8 + 1) * 40 + c_s] = f2bf(pva.y);
      sV[nb][(x8 + 2) * 40 + c_s] = f2bf(pva.z);
      sV[nb][(x8 + 3) * 40 + c_s] = f2bf(pva.w);
      sV[nb][(x8 + 4) * 40 + c_s] = f2bf(pvb.x);
      sV[nb][(x8 + 5) * 40 + c_s] = f2bf(pvb.y);
      sV[nb][(x8 + 6) * 40 + c_s] = f2bf(pvb.z);
      sV[nb][(x8 + 7) * 40 + c_s] = f2bf(pvb.w);
    }
    __syncthreads();
  }

#pragma unroll
  for (int i = 0; i < 2; ++i) {
#pragma unroll
    for (int r = 0; r < 4; ++r) {
      const int o = wv * 32 + i * 16 + q * 4 + r;
      const float bo = bias[o];
#pragma unroll
      for (int j = 0; j < 8; ++j)
        PV[(size_t)o * THW + x0 + j * 16 + m] = acc[i][j][r] + bo;
    }
  }
}

// ---------------------------------------------------------------------------
// t + h fused (v8). The R4 t/h split was a retrospective regression: it
// added an O write+read round-trip and a launch, and the traffic it saved
// didn't matter (latency-bound family, R5 evidence). v8 = v7's h-structure
// (grid 512, 32KB slab, 2 blk/CU, plain launch_bounds) with the t-part
// accumulated directly in registers first (R2's proven coalesced pattern).
// Accumulation order per output unchanged (s=0..7 then p=0..63) -> bitwise
// identical. O is written once, never read here.
// ---------------------------------------------------------------------------
__global__ __launch_bounds__(512) void attn_th2(
    const float* __restrict__ A, const float* __restrict__ PV,
    float* __restrict__ O) {
  const int b = blockIdx.x;  // hd + 8*(chb + 2*(qb + 4*tq)), grid 512
  const int hd = b & 7;
  const int chb = (b >> 3) & 1;
  const int qb = (b >> 4) & 3;
  const int tq = b >> 6;  // 0..7
  const int tid = threadIdx.x;
  const int lane = tid & 63;
  const int wv = tid >> 6;         // 0..7
  const int w4 = (lane & 15) * 4;  // w float-offset (f32x4)
  const int cl = lane >> 4;        // 0..3
  const int q0 = qb * 16 + wv * 2;
  const int c0 = chb * 16;

  __shared__ float slab[2][4 * 16 * 64];  // [buf][pp][c][w] = 32 KB

  const float* __restrict__ Ab = A + (size_t)hd * SS * THW + (size_t)tq * HWP;
  const size_t pvh = (size_t)hd * 32 * THW;
  const float* __restrict__ PVh = PV + pvh;

  f32x4 acc[2][4];  // [qi][g]
#pragma unroll
  for (int qi = 0; qi < 2; ++qi)
#pragma unroll
    for (int g = 0; g < 4; ++g)
      acc[qi][g] = (f32x4){0.f, 0.f, 0.f, 0.f};

  // staging map: thread covers pp = pp0 + 2r (r 0..1) at fixed (c_s, w4s)
  const int w4s = (tid & 15) * 4;
  const int c_s = (tid >> 4) & 15;   // 0..15
  const int pp0 = tid >> 8;          // 0..1
  const float* __restrict__ pvstage =
      PVh + (size_t)(c0 + c_s) * THW + (size_t)tq * HWP + w4s;
  const int sbase = c_s * 64 + w4s;  // float offset within a pp plane (16c*64w)

  // chunk-0 prefetch issued first; completes under the t-part
  f32x4 stg[2];
#pragma unroll
  for (int r = 0; r < 2; ++r)
    stg[r] = *(const f32x4*)&pvstage[(pp0 + 2 * r) * 64];

  // ---- t part (pure streaming, coalesced; pv rows L2/L3-warm) ----
  for (int s = 0; s < 8; ++s) {
#pragma unroll
    for (int qi = 0; qi < 2; ++qi) {
      const int q = q0 + qi;
      const f32x4 a = *(const f32x4*)&Ab[(size_t)s * THW + q * 64 + w4];
#pragma unroll
      for (int g = 0; g < 4; ++g) {
        const int c = c0 + g * 4 + cl;
        const f32x4 v =
            *(const f32x4*)&PVh[(size_t)c * THW + (size_t)s * HWP + q * 64 + w4];
        acc[qi][g] += a * v;
      }
    }
  }

  // write chunk 0
#pragma unroll
  for (int r = 0; r < 2; ++r)
    *(f32x4*)&slab[0][(pp0 + 2 * r) * 1024 + sbase] = stg[r];
  __syncthreads();

  // ---- h part: 16 chunks of 4 p, double-buffered, 1 sync/chunk ----
  for (int ck = 0; ck < 16; ++ck) {
    const int cur = ck & 1;
    if (ck < 15) {
#pragma unroll
      for (int r = 0; r < 2; ++r)
        stg[r] = *(const f32x4*)&pvstage[((ck + 1) * 4 + pp0 + 2 * r) * 64];
    }
#pragma unroll
    for (int pp = 0; pp < 4; ++pp) {
      const int p = ck * 4 + pp;
      f32x4 a[2];
#pragma unroll
      for (int qi = 0; qi < 2; ++qi) {
        const int q = q0 + qi;
        const int row = p - (q < p ? 1 : 0);  // 0..63 (p==q load masked)
        f32x4 av = *(const f32x4*)&Ab[(size_t)(8 + row) * THW + q * 64 + w4];
        if (q == p) av = (f32x4){0.f, 0.f, 0.f, 0.f};
        a[qi] = av;
      }
      f32x4 v[4];
#pragma unroll
      for (int g = 0; g < 4; ++g)
        v[g] = *(const f32x4*)&slab[cur][pp * 1024 + (g * 4 + cl) * 64 + w4];
#pragma unroll
      for (int qi = 0; qi < 2; ++qi)
#pragma unroll
        for (int g = 0; g < 4; ++g)
          acc[qi][g] += a[qi] * v[g];
    }
    if (ck < 15) {
#pragma unroll
      for (int r = 0; r < 2; ++r)
        *(f32x4*)&slab[cur ^ 1][(pp0 + 2 * r) * 1024 + sbase] = stg[r];
    }
    __syncthreads();
  }

  // ---- store (t + h partial; single write, no read) ----
#pragma unroll
  for (int qi = 0; qi < 2; ++qi) {
    const int q = q0 + qi;
#pragma unroll
    for (int g = 0; g < 4; ++g) {
      const int c = c0 + g * 4 + cl;
      *(f32x4*)&O[pvh + (size_t)c * THW + (size_t)tq * HWP + q * 64 + w4] =
          acc[qi][g];
    }
  }
}

// ---------------------------------------------------------------------------
// w axis v2, RMW on O. c-split x2 (16 c per block) -> grid 2048, slab 16KB,
// 256 thr -> 8 blocks/CU (~32 waves/CU) at ~48 VGPR (racc[4]). A_w L2-reads
// duplicate x2 across cw siblings (L3-absorbed; family is latency-bound).
// Accumulation order unchanged (p ascending on top of O) -> bitwise same.
// ---------------------------------------------------------------------------
__global__ __launch_bounds__(256) void attn_w(
    const float* __restrict__ A, const float* __restrict__ PV,
    float* __restrict__ O) {
  const int b = blockIdx.x;  // hb + 16*(cw + 2*(tq + 8*hd)), grid 2048
  const int hb = b & 15;
  const int cw = (b >> 4) & 1;
  const int tq = (b >> 5) & 7;
  const int hd = b >> 8;
  const int tid = threadIdx.x;
  const int wq = tid & 63;
  const int cg = tid >> 6;  // 0..3
  const int h0 = hb * 4;
  const int c0 = cw * 16;

  __shared__ float slab[16 * 64 * 4];  // [c][pw][h4] = 16 KB

  const float* __restrict__ Ab = A + (size_t)hd * SS * THW + (size_t)tq * HWP;
  const size_t pvh = (size_t)hd * 32 * THW;

  // stage pv w-slab (transpose w<->h minor dims), c = c0 + 0..15
#pragma unroll
  for (int i = 0; i < 4; ++i) {
    const int fid = tid + i * 256;     // 0..1023
    const int w4s = (fid & 15) * 4;    // 0..60
    const int h = (fid >> 4) & 3;      // 0..3
    const int c = fid >> 6;            // 0..15 local
    const f32x4 v =
        *(const f32x4*)&PV[pvh + (size_t)(c0 + c) * THW + (size_t)tq * HWP + (h0 + h) * 64 + w4s];
    slab[(c * 64 + w4s + 0) * 4 + h] = v.x;
    slab[(c * 64 + w4s + 1) * 4 + h] = v.y;
    slab[(c * 64 + w4s + 2) * 4 + h] = v.z;
    slab[(c * 64 + w4s + 3) * 4 + h] = v.w;
  }

  // prefetch current O tile (RMW) while staging completes
  f32x4 racc[4];
#pragma unroll
  for (int ci = 0; ci < 4; ++ci) {
    const int c = c0 + cg + ci * 4;
    f32x4 r;
#pragma unroll
    for (int hh = 0; hh < 4; ++hh)
      r[hh] = O[pvh + (size_t)c * THW + (size_t)tq * HWP + (h0 + hh) * 64 + wq];
    racc[ci] = r;
  }
  __syncthreads();

#pragma unroll 4
  for (int p = 0; p < 64; ++p) {
    const int row = 71 + p - (wq <= p ? 1 : 0);  // 70..133, in-bounds always
    const float* pa = Ab + (size_t)row * THW + h0 * 64 + wq;
    f32x4 a;
    a.x = pa[0];
    a.y = pa[64];
    a.z = pa[128];
    a.w = pa[192];
    if (p == wq) a = (f32x4){0.f, 0.f, 0.f, 0.f};
#pragma unroll
    for (int ci = 0; ci < 4; ++ci) {
      const f32x4 v = *(const f32x4*)&slab[(cg + ci * 4) * 256 + p * 4];
      racc[ci] += a * v;
    }
  }

  // ---- store (RMW result) ----
#pragma unroll
  for (int ci = 0; ci < 4; ++ci) {
    const int c = c0 + cg + ci * 4;
#pragma unroll
    for (int hh = 0; hh < 4; ++hh)
      O[pvh + (size_t)c * THW + (size_t)tq * HWP + (h0 + hh) * 64 + wq] = racc[ci][hh];
  }
}

extern "C" void kernel_launch(void* const* d_in, const int* in_sizes, int n_in,
                              void* d_out, int out_size, void* d_ws, size_t ws_size,
                              hipStream_t stream) {
  const float* A = (const float*)d_in[0];     // [8*134][8][64][64]
  const float* V = (const float*)d_in[1];     // [256][8][64][64]
  const float* W = (const float*)d_in[2];     // [256][256] (o, c)
  const float* bias = (const float*)d_in[3];  // [256]
  float* out = (float*)d_out;                 // [256][8][64][64]
  float* pv = (float*)d_ws;                   // 32 MB scratch: pv[o][t][h][w]

  unsigned short* Wbf = (unsigned short*)d_out;  // temp 128 KB, dead after conv

  w2bf<<<dim3(64), 256, 0, stream>>>(W, Wbf);
  conv1x1_v4<<<dim3(256), 512, 0, stream>>>(V, Wbf, bias, pv);
  attn_th2<<<dim3(512), 512, 0, stream>>>(A, pv, out);
  attn_w<<<dim3(2048), 256, 0, stream>>>(A, pv, out);
}

// Round 9
// 347.420 us; speedup vs baseline: 1.0442x; 1.0442x over previous
//
#include <hip/hip_runtime.h>

// Shapes (fixed per setup_inputs): n=1, C=256, t=8, h=64, w=64, heads=8, S=134
#define SS   134
#define HWP  4096     // h*w
#define THW  32768    // t*h*w

typedef float f32x4 __attribute__((ext_vector_type(4)));
typedef short bf16x8 __attribute__((ext_vector_type(8)));
typedef short bf16x4 __attribute__((ext_vector_type(4)));

__device__ __forceinline__ unsigned short f2bf(float f) {
  unsigned int u = __float_as_uint(f);
  u += 0x7fff + ((u >> 16) & 1);  // RNE (inputs are finite normals)
  return (unsigned short)(u >> 16);
}

// ---------------------------------------------------------------------------
// V and W -> bf16, once (streaming). Outputs live in d_out: Vbf [0,16MB),
// Wbf [16MB,16.125MB). attn_t fully overwrites O afterwards; stream order
// (inputs_bf -> conv -> attn_t) makes the aliasing safe. Removes the 16
// f2bf VALU ops per thread per k-step from conv's critical loop and halves
// V's global bytes.
// ---------------------------------------------------------------------------
__global__ __launch_bounds__(256) void inputs_bf(
    const float* __restrict__ V, const float* __restrict__ W,
    unsigned short* __restrict__ Vbf, unsigned short* __restrict__ Wbf) {
  const int b = blockIdx.x;  // grid 8256: 8192 for V (8M floats), 64 for W
  if (b < 8192) {
    const int i = b * 1024 + threadIdx.x * 4;
    const float4 v4 = *(const float4*)&V[i];
    bf16x4 o;
    o.x = (short)f2bf(v4.x);
    o.y = (short)f2bf(v4.y);
    o.z = (short)f2bf(v4.z);
    o.w = (short)f2bf(v4.w);
    *(bf16x4*)&Vbf[i] = o;
  } else {
    const int i = (b - 8192) * 1024 + threadIdx.x * 4;
    const float4 w4 = *(const float4*)&W[i];
    bf16x4 o;
    o.x = (short)f2bf(w4.x);
    o.y = (short)f2bf(w4.y);
    o.z = (short)f2bf(w4.z);
    o.w = (short)f2bf(w4.w);
    *(bf16x4*)&Wbf[i] = o;
  }
}

// ---------------------------------------------------------------------------
// 1x1 conv v5: identical structure/numerics to v4 (W once in 130KB LDS, V
// double-buffered, k ascending, same MFMA chain -> bitwise-identical PV),
// but V staged from pre-converted Vbf: 1 bf16x8 load + 8 u16 LDS stores per
// thread per k-step (was 2 float4 loads + 16 f2bf + 8 stores).
// ---------------------------------------------------------------------------
__global__ __launch_bounds__(512) void conv1x1_v5(
    const unsigned short* __restrict__ Vbf, const unsigned short* __restrict__ Wbf,
    const float* __restrict__ bias, float* __restrict__ PV) {
  __shared__ unsigned short sW[256 * 260];   // 130 KB, row stride 260
  __shared__ unsigned short sV[2][128 * 40]; // [buf][x][c], 2 x 10 KB
  const int tid = threadIdx.x;
  const int x0 = blockIdx.x * 128;  // grid 256
  const int lane = tid & 63;
  const int wv = tid >> 6;   // 0..7
  const int m = lane & 15;   // MFMA free-dim index
  const int q = lane >> 4;   // MFMA quad 0..3

  {
    const int o = tid >> 1;
    const int half = (tid & 1) * 128;
#pragma unroll
    for (int r = 0; r < 16; ++r)
      *(bf16x8*)&sW[o * 260 + half + r * 8] =
          *(const bf16x8*)&Wbf[o * 256 + half + r * 8];
  }

  const int c_s = tid >> 4;        // 0..31
  const int x8 = (tid & 15) * 8;   // 0..120
  const unsigned short* __restrict__ vstage = Vbf + (size_t)c_s * THW + x0 + x8;

  {
    const bf16x8 v8 = *(const bf16x8*)&vstage[0];
#pragma unroll
    for (int e = 0; e < 8; ++e)
      sV[0][(x8 + e) * 40 + c_s] = (unsigned short)v8[e];
  }
  __syncthreads();

  f32x4 acc[2][8];
#pragma unroll
  for (int i = 0; i < 2; ++i)
#pragma unroll
    for (int j = 0; j < 8; ++j)
      acc[i][j] = (f32x4){0.f, 0.f, 0.f, 0.f};

  for (int kk = 0; kk < 8; ++kk) {
    const int cur = kk & 1;
    bf16x8 pv8;
    if (kk < 7) {  // prefetch next V chunk; completes under the MFMAs
      pv8 = *(const bf16x8*)&vstage[(size_t)(kk + 1) * 32 * THW];
    }
    bf16x8 fa[2], fb[8];
#pragma unroll
    for (int i = 0; i < 2; ++i)
      fa[i] = *(const bf16x8*)&sW[(wv * 32 + i * 16 + m) * 260 + kk * 32 + q * 8];
#pragma unroll
    for (int j = 0; j < 8; ++j)
      fb[j] = *(const bf16x8*)&sV[cur][(j * 16 + m) * 40 + q * 8];
#pragma unroll
    for (int i = 0; i < 2; ++i)
#pragma unroll
      for (int j = 0; j < 8; ++j)
        acc[i][j] = __builtin_amdgcn_mfma_f32_16x16x32_bf16(fa[i], fb[j], acc[i][j], 0, 0, 0);
    if (kk < 7) {
      const int nb = cur ^ 1;
#pragma unroll
      for (int e = 0; e < 8; ++e)
        sV[nb][(x8 + e) * 40 + c_s] = (unsigned short)pv8[e];
    }
    __syncthreads();
  }

#pragma unroll
  for (int i = 0; i < 2; ++i) {
#pragma unroll
    for (int r = 0; r < 4; ++r) {
      const int o = wv * 32 + i * 16 + q * 4 + r;
      const float bo = bias[o];
#pragma unroll
      for (int j = 0; j < 8; ++j)
        PV[(size_t)o * THW + x0 + j * 16 + m] = acc[i][j][r] + bo;
    }
  }
}

// ---------------------------------------------------------------------------
// t axis v2 (R7 verbatim). Standalone: PV read exactly once over tq (fusing
// it into attn_h re-reads PV x8 -- R8 regression, do not re-fuse).
// ---------------------------------------------------------------------------
__global__ __launch_bounds__(256) void attn_t(
    const float* __restrict__ A, const float* __restrict__ PV,
    float* __restrict__ O) {
  const int b = blockIdx.x;  // hd + 8*(cb + 4*xt), grid 1024
  const int hd = b & 7;
  const int cb = (b >> 3) & 3;
  const int xt = b >> 5;  // 0..31
  const int tid = threadIdx.x;
  const int xi = xt * 128 + (tid & 31) * 4;  // hw float offset
  const int c = cb * 8 + (tid >> 5);         // 0..31 within head

  const float* __restrict__ At = A + (size_t)hd * SS * THW + xi;
  const size_t pvh = (size_t)hd * 32 * THW;
  const float* __restrict__ pvc = PV + pvh + (size_t)c * THW + xi;

  f32x4 acc[8];
#pragma unroll
  for (int t = 0; t < 8; ++t) acc[t] = (f32x4){0.f, 0.f, 0.f, 0.f};

  for (int s = 0; s < 8; ++s) {
    const f32x4 pvv = *(const f32x4*)&pvc[(size_t)s * HWP];
#pragma unroll
    for (int t = 0; t < 8; ++t) {
      const f32x4 a = *(const f32x4*)&At[(size_t)s * THW + (size_t)t * HWP];
      acc[t] += a * pvv;
    }
  }

#pragma unroll
  for (int t = 0; t < 8; ++t)
    *(f32x4*)&O[pvh + (size_t)c * THW + (size_t)t * HWP + xi] = acc[t];
}

// ---------------------------------------------------------------------------
// h axis v7 (R7 verbatim), RMW on O.
// ---------------------------------------------------------------------------
__global__ __launch_bounds__(512) void attn_h(
    const float* __restrict__ A, const float* __restrict__ PV,
    float* __restrict__ O) {
  const int b = blockIdx.x;  // hd + 8*(chb + 2*(qb + 4*tq)), grid 512
  const int hd = b & 7;
  const int chb = (b >> 3) & 1;
  const int qb = (b >> 4) & 3;
  const int tq = b >> 6;  // 0..7
  const int tid = threadIdx.x;
  const int lane = tid & 63;
  const int wv = tid >> 6;         // 0..7
  const int w4 = (lane & 15) * 4;  // w float-offset (f32x4)
  const int cl = lane >> 4;        // 0..3
  const int q0 = qb * 16 + wv * 2;
  const int c0 = chb * 16;

  __shared__ float slab[2][4 * 16 * 64];  // [buf][pp][c][w] = 32 KB

  const float* __restrict__ Ab = A + (size_t)hd * SS * THW + (size_t)tq * HWP;
  const size_t pvh = (size_t)hd * 32 * THW;
  const float* __restrict__ PVh = PV + pvh;

  // init acc from O (t-part, RMW); issued first so latency hides under staging
  f32x4 acc[2][4];  // [qi][g]
#pragma unroll
  for (int qi = 0; qi < 2; ++qi) {
    const int q = q0 + qi;
#pragma unroll
    for (int g = 0; g < 4; ++g) {
      const int c = c0 + g * 4 + cl;
      acc[qi][g] =
          *(const f32x4*)&O[pvh + (size_t)c * THW + (size_t)tq * HWP + q * 64 + w4];
    }
  }

  // staging map: thread covers pp = pp0 + 2r (r 0..1) at fixed (c_s, w4s)
  const int w4s = (tid & 15) * 4;
  const int c_s = (tid >> 4) & 15;   // 0..15
  const int pp0 = tid >> 8;          // 0..1
  const float* __restrict__ pvstage =
      PVh + (size_t)(c0 + c_s) * THW + (size_t)tq * HWP + w4s;
  const int sbase = c_s * 64 + w4s;  // float offset within a pp plane (16c*64w)

  // chunk-0 prefetch (p = 0..3)
  f32x4 stg[2];
#pragma unroll
  for (int r = 0; r < 2; ++r)
    stg[r] = *(const f32x4*)&pvstage[(pp0 + 2 * r) * 64];
#pragma unroll
  for (int r = 0; r < 2; ++r)
    *(f32x4*)&slab[0][(pp0 + 2 * r) * 1024 + sbase] = stg[r];
  __syncthreads();

  // ---- h axis: 16 chunks of 4 p, double-buffered, 1 sync/chunk ----
  for (int ck = 0; ck < 16; ++ck) {
    const int cur = ck & 1;
    if (ck < 15) {
#pragma unroll
      for (int r = 0; r < 2; ++r)
        stg[r] = *(const f32x4*)&pvstage[((ck + 1) * 4 + pp0 + 2 * r) * 64];
    }
#pragma unroll
    for (int pp = 0; pp < 4; ++pp) {
      const int p = ck * 4 + pp;
      f32x4 a[2];
#pragma unroll
      for (int qi = 0; qi < 2; ++qi) {
        const int q = q0 + qi;
        const int row = p - (q < p ? 1 : 0);  // 0..63 (p==q load masked)
        f32x4 av = *(const f32x4*)&Ab[(size_t)(8 + row) * THW + q * 64 + w4];
        if (q == p) av = (f32x4){0.f, 0.f, 0.f, 0.f};
        a[qi] = av;
      }
      f32x4 v[4];
#pragma unroll
      for (int g = 0; g < 4; ++g)
        v[g] = *(const f32x4*)&slab[cur][pp * 1024 + (g * 4 + cl) * 64 + w4];
#pragma unroll
      for (int qi = 0; qi < 2; ++qi)
#pragma unroll
        for (int g = 0; g < 4; ++g)
          acc[qi][g] += a[qi] * v[g];
    }
    if (ck < 15) {
#pragma unroll
      for (int r = 0; r < 2; ++r)
        *(f32x4*)&slab[cur ^ 1][(pp0 + 2 * r) * 1024 + sbase] = stg[r];
    }
    __syncthreads();
  }

  // ---- store (t + h partial) ----
#pragma unroll
  for (int qi = 0; qi < 2; ++qi) {
    const int q = q0 + qi;
#pragma unroll
    for (int g = 0; g < 4; ++g) {
      const int c = c0 + g * 4 + cl;
      *(f32x4*)&O[pvh + (size_t)c * THW + (size_t)tq * HWP + q * 64 + w4] =
          acc[qi][g];
    }
  }
}

// ---------------------------------------------------------------------------
// w axis v2 (R7 verbatim), RMW on O.
// ---------------------------------------------------------------------------
__global__ __launch_bounds__(256) void attn_w(
    const float* __restrict__ A, const float* __restrict__ PV,
    float* __restrict__ O) {
  const int b = blockIdx.x;  // hb + 16*(cw + 2*(tq + 8*hd)), grid 2048
  const int hb = b & 15;
  const int cw = (b >> 4) & 1;
  const int tq = (b >> 5) & 7;
  const int hd = b >> 8;
  const int tid = threadIdx.x;
  const int wq = tid & 63;
  const int cg = tid >> 6;  // 0..3
  const int h0 = hb * 4;
  const int c0 = cw * 16;

  __shared__ float slab[16 * 64 * 4];  // [c][pw][h4] = 16 KB

  const float* __restrict__ Ab = A + (size_t)hd * SS * THW + (size_t)tq * HWP;
  const size_t pvh = (size_t)hd * 32 * THW;

  // stage pv w-slab (transpose w<->h minor dims), c = c0 + 0..15
#pragma unroll
  for (int i = 0; i < 4; ++i) {
    const int fid = tid + i * 256;     // 0..1023
    const int w4s = (fid & 15) * 4;    // 0..60
    const int h = (fid >> 4) & 3;      // 0..3
    const int c = fid >> 6;            // 0..15 local
    const f32x4 v =
        *(const f32x4*)&PV[pvh + (size_t)(c0 + c) * THW + (size_t)tq * HWP + (h0 + h) * 64 + w4s];
    slab[(c * 64 + w4s + 0) * 4 + h] = v.x;
    slab[(c * 64 + w4s + 1) * 4 + h] = v.y;
    slab[(c * 64 + w4s + 2) * 4 + h] = v.z;
    slab[(c * 64 + w4s + 3) * 4 + h] = v.w;
  }

  // prefetch current O tile (RMW) while staging completes
  f32x4 racc[4];
#pragma unroll
  for (int ci = 0; ci < 4; ++ci) {
    const int c = c0 + cg + ci * 4;
    f32x4 r;
#pragma unroll
    for (int hh = 0; hh < 4; ++hh)
      r[hh] = O[pvh + (size_t)c * THW + (size_t)tq * HWP + (h0 + hh) * 64 + wq];
    racc[ci] = r;
  }
  __syncthreads();

#pragma unroll 4
  for (int p = 0; p < 64; ++p) {
    const int row = 71 + p - (wq <= p ? 1 : 0);  // 70..133, in-bounds always
    const float* pa = Ab + (size_t)row * THW + h0 * 64 + wq;
    f32x4 a;
    a.x = pa[0];
    a.y = pa[64];
    a.z = pa[128];
    a.w = pa[192];
    if (p == wq) a = (f32x4){0.f, 0.f, 0.f, 0.f};
#pragma unroll
    for (int ci = 0; ci < 4; ++ci) {
      const f32x4 v = *(const f32x4*)&slab[(cg + ci * 4) * 256 + p * 4];
      racc[ci] += a * v;
    }
  }

  // ---- store (RMW result) ----
#pragma unroll
  for (int ci = 0; ci < 4; ++ci) {
    const int c = c0 + cg + ci * 4;
#pragma unroll
    for (int hh = 0; hh < 4; ++hh)
      O[pvh + (size_t)c * THW + (size_t)tq * HWP + (h0 + hh) * 64 + wq] = racc[ci][hh];
  }
}

extern "C" void kernel_launch(void* const* d_in, const int* in_sizes, int n_in,
                              void* d_out, int out_size, void* d_ws, size_t ws_size,
                              hipStream_t stream) {
  const float* A = (const float*)d_in[0];     // [8*134][8][64][64]
  const float* V = (const float*)d_in[1];     // [256][8][64][64]
  const float* W = (const float*)d_in[2];     // [256][256] (o, c)
  const float* bias = (const float*)d_in[3];  // [256]
  float* out = (float*)d_out;                 // [256][8][64][64]
  float* pv = (float*)d_ws;                   // 32 MB scratch: pv[o][t][h][w]

  unsigned short* Vbf = (unsigned short*)d_out;       // 16 MB, dead after conv
  unsigned short* Wbf = Vbf + (size_t)8 * 1024 * 1024;  // 128 KB at +16 MB

  inputs_bf<<<dim3(8256), 256, 0, stream>>>(V, W, Vbf, Wbf);
  conv1x1_v5<<<dim3(256), 512, 0, stream>>>(Vbf, Wbf, bias, pv);
  attn_t<<<dim3(1024), 256, 0, stream>>>(A, pv, out);
  attn_h<<<dim3(512), 512, 0, stream>>>(A, pv, out);
  attn_w<<<dim3(2048), 256, 0, stream>>>(A, pv, out);
}

// Round 10
// 329.204 us; speedup vs baseline: 1.1020x; 1.0553x over previous
//
#include <hip/hip_runtime.h>

// Shapes (fixed per setup_inputs): n=1, C=256, t=8, h=64, w=64, heads=8, S=134
#define SS   134
#define HWP  4096     // h*w
#define THW  32768    // t*h*w

typedef float f32x4 __attribute__((ext_vector_type(4)));
typedef short bf16x8 __attribute__((ext_vector_type(8)));
typedef short bf16x4 __attribute__((ext_vector_type(4)));

__device__ __forceinline__ unsigned short f2bf(float f) {
  unsigned int u = __float_as_uint(f);
  u += 0x7fff + ((u >> 16) & 1);  // RNE (inputs are finite normals)
  return (unsigned short)(u >> 16);
}

// ---------------------------------------------------------------------------
// W -> bf16, once. Wbf lives in d_out (128 KB): attn_tw fully overwrites O
// afterwards; stream order (w2bf -> conv -> attn_tw) makes aliasing safe.
// (R9 lesson: do NOT pre-convert V — it doubles V traffic for VALU work
// that hides under MFMA anyway.)
// ---------------------------------------------------------------------------
__global__ __launch_bounds__(256) void w2bf(const float* __restrict__ W,
                                            unsigned short* __restrict__ Wbf) {
  const int i = (blockIdx.x * 256 + threadIdx.x) * 4;  // grid 64 -> 65536
  const float4 w4 = *(const float4*)&W[i];
  bf16x4 b;
  b.x = (short)f2bf(w4.x);
  b.y = (short)f2bf(w4.y);
  b.z = (short)f2bf(w4.z);
  b.w = (short)f2bf(w4.w);
  *(bf16x4*)&Wbf[i] = b;
}

// ---------------------------------------------------------------------------
// 1x1 conv v4 (R7 verbatim): W staged once into 130KB LDS, V dbuf.
// ---------------------------------------------------------------------------
__global__ __launch_bounds__(512) void conv1x1_v4(
    const float* __restrict__ V, const unsigned short* __restrict__ Wbf,
    const float* __restrict__ bias, float* __restrict__ PV) {
  __shared__ unsigned short sW[256 * 260];   // 130 KB, row stride 260
  __shared__ unsigned short sV[2][128 * 40]; // [buf][x][c], 2 x 10 KB
  const int tid = threadIdx.x;
  const int x0 = blockIdx.x * 128;  // grid 256
  const int lane = tid & 63;
  const int wv = tid >> 6;   // 0..7
  const int m = lane & 15;   // MFMA free-dim index
  const int q = lane >> 4;   // MFMA quad 0..3

  {
    const int o = tid >> 1;
    const int half = (tid & 1) * 128;
#pragma unroll
    for (int r = 0; r < 16; ++r)
      *(bf16x8*)&sW[o * 260 + half + r * 8] =
          *(const bf16x8*)&Wbf[o * 256 + half + r * 8];
  }

  const int c_s = tid >> 4;
  const int x8 = (tid & 15) * 8;
  const float* __restrict__ vstage = V + (size_t)c_s * THW + x0 + x8;

  {
    const float4 va = *(const float4*)&vstage[0];
    const float4 vb = *(const float4*)&vstage[4];
    sV[0][(x8 + 0) * 40 + c_s] = f2bf(va.x);
    sV[0][(x8 + 1) * 40 + c_s] = f2bf(va.y);
    sV[0][(x8 + 2) * 40 + c_s] = f2bf(va.z);
    sV[0][(x8 + 3) * 40 + c_s] = f2bf(va.w);
    sV[0][(x8 + 4) * 40 + c_s] = f2bf(vb.x);
    sV[0][(x8 + 5) * 40 + c_s] = f2bf(vb.y);
    sV[0][(x8 + 6) * 40 + c_s] = f2bf(vb.z);
    sV[0][(x8 + 7) * 40 + c_s] = f2bf(vb.w);
  }
  __syncthreads();

  f32x4 acc[2][8];
#pragma unroll
  for (int i = 0; i < 2; ++i)
#pragma unroll
    for (int j = 0; j < 8; ++j)
      acc[i][j] = (f32x4){0.f, 0.f, 0.f, 0.f};

  for (int kk = 0; kk < 8; ++kk) {
    const int cur = kk & 1;
    float4 pva, pvb;
    if (kk < 7) {
      pva = *(const float4*)&vstage[(size_t)(kk + 1) * 32 * THW];
      pvb = *(const float4*)&vstage[(size_t)(kk + 1) * 32 * THW + 4];
    }
    bf16x8 fa[2], fb[8];
#pragma unroll
    for (int i = 0; i < 2; ++i)
      fa[i] = *(const bf16x8*)&sW[(wv * 32 + i * 16 + m) * 260 + kk * 32 + q * 8];
#pragma unroll
    for (int j = 0; j < 8; ++j)
      fb[j] = *(const bf16x8*)&sV[cur][(j * 16 + m) * 40 + q * 8];
#pragma unroll
    for (int i = 0; i < 2; ++i)
#pragma unroll
      for (int j = 0; j < 8; ++j)
        acc[i][j] = __builtin_amdgcn_mfma_f32_16x16x32_bf16(fa[i], fb[j], acc[i][j], 0, 0, 0);
    if (kk < 7) {
      const int nb = cur ^ 1;
      sV[nb][(x8 + 0) * 40 + c_s] = f2bf(pva.x);
      sV[nb][(x8 + 1) * 40 + c_s] = f2bf(pva.y);
      sV[nb][(x8 + 2) * 40 + c_s] = f2bf(pva.z);
      sV[nb][(x8 + 3) * 40 + c_s] = f2bf(pva.w);
      sV[nb][(x8 + 4) * 40 + c_s] = f2bf(pvb.x);
      sV[nb][(x8 + 5) * 40 + c_s] = f2bf(pvb.y);
      sV[nb][(x8 + 6) * 40 + c_s] = f2bf(pvb.z);
      sV[nb][(x8 + 7) * 40 + c_s] = f2bf(pvb.w);
    }
    __syncthreads();
  }

#pragma unroll
  for (int i = 0; i < 2; ++i) {
#pragma unroll
    for (int r = 0; r < 4; ++r) {
      const int o = wv * 32 + i * 16 + q * 4 + r;
      const float bo = bias[o];
#pragma unroll
      for (int j = 0; j < 8; ++j)
        PV[(size_t)o * THW + x0 + j * 16 + m] = acc[i][j][r] + bo;
    }
  }
}

// ---------------------------------------------------------------------------
// t + w fused, writes O (no read). Key insight vs the failed R8 t+h fusion:
// the w-kernel's block decomposition (hd, tq, h-strip of 4) tiles pv with
// ZERO duplication for the t-part — each pv[c][s][h][w] element is read by
// exactly one (hb) block. Fusing t here:
//   - deletes the attn_t kernel, its 32MB pv read, its 32MB O write, and
//     attn_w's 32MB O read (O round-trip eliminated);
//   - A_t read exactly once (33MB, was x4 = 132MB in split attn_t).
// Also drops the R7 cw-split (A_w 128->64MB): full c=32, racc[8], slab 32KB
// -> ~4 blocks/CU. Output = t-part + w-part; attn_h adds the h-part after
// (t->w->h reorder vs ref's t->h->w: ~1ulp perturbation, within tolerance).
// ---------------------------------------------------------------------------
__global__ __launch_bounds__(256) void attn_tw(
    const float* __restrict__ A, const float* __restrict__ PV,
    float* __restrict__ O) {
  const int b = blockIdx.x;  // hb + 16*tq + 128*hd, grid 1024
  const int hb = b & 15;
  const int tq = (b >> 4) & 7;
  const int hd = b >> 7;
  const int tid = threadIdx.x;
  const int wq = tid & 63;
  const int cg = tid >> 6;  // 0..3
  const int h0 = hb * 4;

  __shared__ float slab[32 * 64 * 4];  // [c][pw][h4] = 32 KB

  const float* __restrict__ Ab = A + (size_t)hd * SS * THW + (size_t)tq * HWP;
  const size_t pvh = (size_t)hd * 32 * THW;

  // ---- stage pv w-slab (transpose w<->h minor dims), c = 0..31 ----
#pragma unroll
  for (int i = 0; i < 8; ++i) {
    const int fid = tid + i * 256;     // 0..2047
    const int w4s = (fid & 15) * 4;    // 0..60
    const int h = (fid >> 4) & 3;      // 0..3
    const int c = fid >> 6;            // 0..31
    const f32x4 v =
        *(const f32x4*)&PV[pvh + (size_t)c * THW + (size_t)tq * HWP + (h0 + h) * 64 + w4s];
    slab[(c * 64 + w4s + 0) * 4 + h] = v.x;
    slab[(c * 64 + w4s + 1) * 4 + h] = v.y;
    slab[(c * 64 + w4s + 2) * 4 + h] = v.z;
    slab[(c * 64 + w4s + 3) * 4 + h] = v.w;
  }

  // ---- t-part into racc (overlaps slab staging; no slab use here) ----
  // racc[ci][hh] = sum_s A_t[s][tq][h0+hh][wq] * pv[c][s][h0+hh][wq]
  f32x4 racc[8];
#pragma unroll
  for (int ci = 0; ci < 8; ++ci) racc[ci] = (f32x4){0.f, 0.f, 0.f, 0.f};

  for (int s = 0; s < 8; ++s) {
    const float* pa = Ab + (size_t)s * THW + h0 * 64 + wq;
    f32x4 a;
    a.x = pa[0];
    a.y = pa[64];
    a.z = pa[128];
    a.w = pa[192];
#pragma unroll
    for (int ci = 0; ci < 8; ++ci) {
      const int c = cg + ci * 4;
      const float* pp = &PV[pvh + (size_t)c * THW + (size_t)s * HWP + h0 * 64 + wq];
      f32x4 v;
      v.x = pp[0];
      v.y = pp[64];
      v.z = pp[128];
      v.w = pp[192];
      racc[ci] += a * v;
    }
  }
  __syncthreads();

  // ---- w-part: weight row per (p, lane) ----
#pragma unroll 4
  for (int p = 0; p < 64; ++p) {
    const int row = 71 + p - (wq <= p ? 1 : 0);  // 70..133, in-bounds always
    const float* pa = Ab + (size_t)row * THW + h0 * 64 + wq;
    f32x4 a;
    a.x = pa[0];
    a.y = pa[64];
    a.z = pa[128];
    a.w = pa[192];
    if (p == wq) a = (f32x4){0.f, 0.f, 0.f, 0.f};
#pragma unroll
    for (int ci = 0; ci < 8; ++ci) {
      const f32x4 v = *(const f32x4*)&slab[(cg + ci * 4) * 256 + p * 4];
      racc[ci] += a * v;
    }
  }

  // ---- store (single write; attn_h RMWs the h-part on top) ----
#pragma unroll
  for (int ci = 0; ci < 8; ++ci) {
    const int c = cg + ci * 4;
#pragma unroll
    for (int hh = 0; hh < 4; ++hh)
      O[pvh + (size_t)c * THW + (size_t)tq * HWP + (h0 + hh) * 64 + wq] = racc[ci][hh];
  }
}

// ---------------------------------------------------------------------------
// h axis v7 (R7 verbatim), RMW on O (now adds h-part on top of t+w).
// ---------------------------------------------------------------------------
__global__ __launch_bounds__(512) void attn_h(
    const float* __restrict__ A, const float* __restrict__ PV,
    float* __restrict__ O) {
  const int b = blockIdx.x;  // hd + 8*(chb + 2*(qb + 4*tq)), grid 512
  const int hd = b & 7;
  const int chb = (b >> 3) & 1;
  const int qb = (b >> 4) & 3;
  const int tq = b >> 6;  // 0..7
  const int tid = threadIdx.x;
  const int lane = tid & 63;
  const int wv = tid >> 6;         // 0..7
  const int w4 = (lane & 15) * 4;  // w float-offset (f32x4)
  const int cl = lane >> 4;        // 0..3
  const int q0 = qb * 16 + wv * 2;
  const int c0 = chb * 16;

  __shared__ float slab[2][4 * 16 * 64];  // [buf][pp][c][w] = 32 KB

  const float* __restrict__ Ab = A + (size_t)hd * SS * THW + (size_t)tq * HWP;
  const size_t pvh = (size_t)hd * 32 * THW;
  const float* __restrict__ PVh = PV + pvh;

  // init acc from O (t+w part, RMW); issued first so latency hides under staging
  f32x4 acc[2][4];  // [qi][g]
#pragma unroll
  for (int qi = 0; qi < 2; ++qi) {
    const int q = q0 + qi;
#pragma unroll
    for (int g = 0; g < 4; ++g) {
      const int c = c0 + g * 4 + cl;
      acc[qi][g] =
          *(const f32x4*)&O[pvh + (size_t)c * THW + (size_t)tq * HWP + q * 64 + w4];
    }
  }

  // staging map: thread covers pp = pp0 + 2r (r 0..1) at fixed (c_s, w4s)
  const int w4s = (tid & 15) * 4;
  const int c_s = (tid >> 4) & 15;   // 0..15
  const int pp0 = tid >> 8;          // 0..1
  const float* __restrict__ pvstage =
      PVh + (size_t)(c0 + c_s) * THW + (size_t)tq * HWP + w4s;
  const int sbase = c_s * 64 + w4s;  // float offset within a pp plane (16c*64w)

  // chunk-0 prefetch (p = 0..3)
  f32x4 stg[2];
#pragma unroll
  for (int r = 0; r < 2; ++r)
    stg[r] = *(const f32x4*)&pvstage[(pp0 + 2 * r) * 64];
#pragma unroll
  for (int r = 0; r < 2; ++r)
    *(f32x4*)&slab[0][(pp0 + 2 * r) * 1024 + sbase] = stg[r];
  __syncthreads();

  // ---- h axis: 16 chunks of 4 p, double-buffered, 1 sync/chunk ----
  for (int ck = 0; ck < 16; ++ck) {
    const int cur = ck & 1;
    if (ck < 15) {
#pragma unroll
      for (int r = 0; r < 2; ++r)
        stg[r] = *(const f32x4*)&pvstage[((ck + 1) * 4 + pp0 + 2 * r) * 64];
    }
#pragma unroll
    for (int pp = 0; pp < 4; ++pp) {
      const int p = ck * 4 + pp;
      f32x4 a[2];
#pragma unroll
      for (int qi = 0; qi < 2; ++qi) {
        const int q = q0 + qi;
        const int row = p - (q < p ? 1 : 0);  // 0..63 (p==q load masked)
        f32x4 av = *(const f32x4*)&Ab[(size_t)(8 + row) * THW + q * 64 + w4];
        if (q == p) av = (f32x4){0.f, 0.f, 0.f, 0.f};
        a[qi] = av;
      }
      f32x4 v[4];
#pragma unroll
      for (int g = 0; g < 4; ++g)
        v[g] = *(const f32x4*)&slab[cur][pp * 1024 + (g * 4 + cl) * 64 + w4];
#pragma unroll
      for (int qi = 0; qi < 2; ++qi)
#pragma unroll
        for (int g = 0; g < 4; ++g)
          acc[qi][g] += a[qi] * v[g];
    }
    if (ck < 15) {
#pragma unroll
      for (int r = 0; r < 2; ++r)
        *(f32x4*)&slab[cur ^ 1][(pp0 + 2 * r) * 1024 + sbase] = stg[r];
    }
    __syncthreads();
  }

  // ---- store (t + w + h) ----
#pragma unroll
  for (int qi = 0; qi < 2; ++qi) {
    const int q = q0 + qi;
#pragma unroll
    for (int g = 0; g < 4; ++g) {
      const int c = c0 + g * 4 + cl;
      *(f32x4*)&O[pvh + (size_t)c * THW + (size_t)tq * HWP + q * 64 + w4] =
          acc[qi][g];
    }
  }
}

extern "C" void kernel_launch(void* const* d_in, const int* in_sizes, int n_in,
                              void* d_out, int out_size, void* d_ws, size_t ws_size,
                              hipStream_t stream) {
  const float* A = (const float*)d_in[0];     // [8*134][8][64][64]
  const float* V = (const float*)d_in[1];     // [256][8][64][64]
  const float* W = (const float*)d_in[2];     // [256][256] (o, c)
  const float* bias = (const float*)d_in[3];  // [256]
  float* out = (float*)d_out;                 // [256][8][64][64]
  float* pv = (float*)d_ws;                   // 32 MB scratch: pv[o][t][h][w]

  unsigned short* Wbf = (unsigned short*)d_out;  // temp 128 KB, dead after conv

  w2bf<<<dim3(64), 256, 0, stream>>>(W, Wbf);
  conv1x1_v4<<<dim3(256), 512, 0, stream>>>(V, Wbf, bias, pv);
  attn_tw<<<dim3(1024), 256, 0, stream>>>(A, pv, out);
  attn_h<<<dim3(512), 512, 0, stream>>>(A, pv, out);
}